// Round 12
// baseline (400.225 us; speedup 1.0000x reference)
//
#include <hip/hip_runtime.h>
#include <stdint.h>

typedef unsigned short u16;
typedef __bf16 bf16x8 __attribute__((ext_vector_type(8)));
typedef float f32x16 __attribute__((ext_vector_type(16)));

#define K_DIM 4096
#define N_OUT 4096
#define M_ROWS 8192

// ---------- helpers ----------

__device__ __forceinline__ u16 f2bf(float f) {
    uint32_t u = __builtin_bit_cast(uint32_t, f);
    u += 0x7fffu + ((u >> 16) & 1u);
    return (u16)(u >> 16);
}

__device__ __forceinline__ void gload_lds16(const void* g, void* l) {
    __builtin_amdgcn_global_load_lds(
        (const __attribute__((address_space(1))) void*)g,
        (__attribute__((address_space(3))) void*)l,
        16, 0, 0);
}

__device__ __forceinline__ int mask_is_int32(const void* maskp) {
    const uint32_t* u = (const uint32_t*)maskp;
    int ok = 1;
#pragma unroll
    for (int g = 0; g < 16; ++g) ok &= (u[g] <= 1u);
    return ok;
}

// ---------- fused prep kernel (r9; ~75us, at BW floor) ----------

__global__ __launch_bounds__(256) void prep_kernel(const float* __restrict__ x,
                                                   u16* __restrict__ xb,
                                                   const int* __restrict__ wq,
                                                   const float* __restrict__ qscale,
                                                   const float* __restrict__ qzero,
                                                   const float* __restrict__ theta,
                                                   const void* __restrict__ maskp,
                                                   u16* __restrict__ wb) {
    if (blockIdx.x < 16384) {
        size_t t = (size_t)blockIdx.x * 256 + threadIdx.x;
        const float4* p = (const float4*)x + t * 2;
        float4 a = p[0], b = p[1];
        union { u16 u[8]; uint4 v; } o;
        o.u[0] = f2bf(a.x); o.u[1] = f2bf(a.y); o.u[2] = f2bf(a.z); o.u[3] = f2bf(a.w);
        o.u[4] = f2bf(b.x); o.u[5] = f2bf(b.y); o.u[6] = f2bf(b.z); o.u[7] = f2bf(b.w);
        ((uint4*)xb)[t] = o.v;
    } else {
        const int mi32 = mask_is_int32(maskp);
        size_t t = (size_t)(blockIdx.x - 16384) * 256 + threadIdx.x;
        size_t base = t * 8;
        int o = (int)(base >> 12);
        float s = qscale[o], z = qzero[o];

        int4 q0 = ((const int4*)wq)[t * 2];
        int4 q1 = ((const int4*)wq)[t * 2 + 1];
        float4 th0 = ((const float4*)theta)[t * 2];
        float4 th1 = ((const float4*)theta)[t * 2 + 1];

        int mv[8];
        if (mi32) {
            int4 m0 = ((const int4*)maskp)[t * 2];
            int4 m1 = ((const int4*)maskp)[t * 2 + 1];
            mv[0] = m0.x; mv[1] = m0.y; mv[2] = m0.z; mv[3] = m0.w;
            mv[4] = m1.x; mv[5] = m1.y; mv[6] = m1.z; mv[7] = m1.w;
        } else {
            uint2 mm = ((const uint2*)maskp)[t];
#pragma unroll
            for (int j = 0; j < 4; ++j) mv[j] = (mm.x >> (8 * j)) & 0xff;
#pragma unroll
            for (int j = 0; j < 4; ++j) mv[4 + j] = (mm.y >> (8 * j)) & 0xff;
        }

        float w[8];
        w[0] = mv[0] ? ((float)q0.x - z) * s : th0.x;
        w[1] = mv[1] ? ((float)q0.y - z) * s : th0.y;
        w[2] = mv[2] ? ((float)q0.z - z) * s : th0.z;
        w[3] = mv[3] ? ((float)q0.w - z) * s : th0.w;
        w[4] = mv[4] ? ((float)q1.x - z) * s : th1.x;
        w[5] = mv[5] ? ((float)q1.y - z) * s : th1.y;
        w[6] = mv[6] ? ((float)q1.z - z) * s : th1.z;
        w[7] = mv[7] ? ((float)q1.w - z) * s : th1.w;

        union { u16 u[8]; uint4 v; } ob;
#pragma unroll
        for (int j = 0; j < 8; ++j) ob.u[j] = f2bf(w[j]);
        ((uint4*)wb)[t] = ob.v;
    }
}

// ---------- 256x256 GEMM, 32x32x16 MFMA, full-line LDS regions (r12) ----------
//
// Skeleton = r10's proven 8-phase read-ahead schedule (stage slots, vmcnt(4)@
// P1/3/5/7, plane->phase map 1:1). Shape 16x16x32 -> 32x32x16 (+15% ceiling:
// 2075->2382 TF; 8 MFMA/phase/wave instead of 16; frag regs 64->48 VGPR).
// LDS plane (16 KiB, K=32): [kstep t(2)][khalf h(2)][256 slots x 16B]; slot s
// of region (t,h) stores row s^(h<<2), k = plane_k + t*16 + h*8 + [0,8).
// FULL-LINE law (6 datapoints r2/r3/r5/r6/r7+/r10): reads covering full 64B
// lines = 0 conflicts; half-line = 4/read flag + ~10% loss. Frag read here =
// 64 consecutive slots = 16 full lines; ^(h<<2) makes lane pairs (l,l+32)
// bank-disjoint (verified consecutive-8 AND pair-32 groupings).
// Staging: gload_lds linear 1024B dests; row-XOR folded into per-lane GLOBAL
// source row (rule #21 both-sides); region (t,h) per wave-pair: t=wave>>2,
// h=(wave>>1)&1, blocks (wave&1)*128 + {0,64}.
// Phases (iter j; planes pl0=b0k0,pl1=b0k1,pl2=b1k0,pl3=b1k1; sets A/B alt):
//   P1: MFMA8(A);VMW4; RD(B,pl0,t1); SA(1,1,t1)   P2: MFMA8(B); RD(A,pl1,t0); SB(1,1,t1)
//   P3: MFMA8(A);VMW4; RD(B,pl1,t1); SA(0,0,t2)   P4: MFMA8(B); RD(A,pl2,t0); SB(0,0,t2)
//   P5: MFMA8(A);VMW4; RD(B,pl2,t1); SA(0,1,t2)   P6: MFMA8(B); RD(A,pl3,t0); SB(0,1,t2)
//   P7: MFMA8(A);VMW4; RD(B,pl3,t1); SA(1,0,t3)   P8: MFMA8(B); RD(A,pl0,t0)'; SB(1,0,t3)
// Read/stage slots = r10's verified hazard table (plane granularity unchanged).
// launch_bounds(512,2) frozen (r8: (512,4) = spill catastrophe).
// Epilogue = r5's correctness-proven 32x32 C/D map: col=l&31,
// row=(reg&3)+8*(reg>>2)+4*(l>>5).

__global__ __launch_bounds__(512, 2) void gemm8_kernel(const u16* __restrict__ xb,
                                                       const u16* __restrict__ wb,
                                                       const float* __restrict__ bias,
                                                       float* __restrict__ out) {
    __shared__ u16 lds[65536];  // 128 KiB: A planes [0,32768), B planes [32768,65536)

    const int tid = threadIdx.x;
    const int lane = tid & 63, wave = tid >> 6;
    const int wm = wave >> 2, wn = wave & 3;
    const int n0 = blockIdx.x * 256;
    const int m0 = blockIdx.y * 256;

    // fragment-read addressing (u16 units)
    const int xr = (lane & 31) ^ ((lane >> 5) << 2);   // row bits with h-XOR
    const int aOff = (lane >> 5) * 2048 + (wm * 128 + xr) * 8;
    const int bOff = 32768 + (lane >> 5) * 2048 + (wn * 64 + xr) * 8;

    // stage addressing: wave-pair regions
    const int hS = (wave >> 1) & 1, tS = wave >> 2;
    const int dst0 = (wave >> 1) * 2048 + (wave & 1) * 1024;   // u16, plane-rel
    const int dst1 = dst0 + 512;
    const int srow0 = (wave & 1) * 128 + (lane ^ (hS << 2));
    const int srow1 = srow0 + 64;
    const int scol = tS * 16 + hS * 8;
    const u16* gA0 = xb + (size_t)(m0 + srow0) * K_DIM + scol;
    const u16* gA1 = xb + (size_t)(m0 + srow1) * K_DIM + scol;
    const u16* gB0 = wb + (size_t)(n0 + srow0) * K_DIM + scol;
    const u16* gB1 = wb + (size_t)(n0 + srow1) * K_DIM + scol;

    f32x16 acc[4][2];
#pragma unroll
    for (int m = 0; m < 4; ++m)
#pragma unroll
        for (int n = 0; n < 2; ++n) acc[m][n] = (f32x16)(0.f);

    // double-buffered fragment sets (static names, rule #20)
    bf16x8 afA0, afA1, afA2, afA3, bfA0, bfA1;
    bf16x8 afB0, afB1, afB2, afB3, bfB0, bfB1;

#define SA(BUF, KH, KT) { \
    const size_t kofs = (size_t)((KT) * 64 + (KH) * 32); \
    const int pl = ((BUF) * 2 + (KH)) * 8192; \
    gload_lds16(gA0 + kofs, &lds[pl + dst0]); \
    gload_lds16(gA1 + kofs, &lds[pl + dst1]); }
#define SB(BUF, KH, KT) { \
    const size_t kofs = (size_t)((KT) * 64 + (KH) * 32); \
    const int pl = 32768 + ((BUF) * 2 + (KH)) * 8192; \
    gload_lds16(gB0 + kofs, &lds[pl + dst0]); \
    gload_lds16(gB1 + kofs, &lds[pl + dst1]); }
// RD: load set S's 4 A-frags + 2 B-frags for (plane PL, kstep T)
#define RD(S, PL, T) { \
    const int rb = (PL) * 8192 + (T) * 4096; \
    af##S##0 = *(const bf16x8*)&lds[rb + aOff]; \
    af##S##1 = *(const bf16x8*)&lds[rb + 256 + aOff]; \
    af##S##2 = *(const bf16x8*)&lds[rb + 512 + aOff]; \
    af##S##3 = *(const bf16x8*)&lds[rb + 768 + aOff]; \
    bf##S##0 = *(const bf16x8*)&lds[rb + bOff]; \
    bf##S##1 = *(const bf16x8*)&lds[rb + 256 + bOff]; }
#define MF(A, B, C) __builtin_amdgcn_mfma_f32_32x32x16_bf16(A, B, C, 0, 0, 0)
#define MFMA8(S) { \
    __builtin_amdgcn_s_setprio(1); \
    acc[0][0] = MF(af##S##0, bf##S##0, acc[0][0]); \
    acc[0][1] = MF(af##S##0, bf##S##1, acc[0][1]); \
    acc[1][0] = MF(af##S##1, bf##S##0, acc[1][0]); \
    acc[1][1] = MF(af##S##1, bf##S##1, acc[1][1]); \
    acc[2][0] = MF(af##S##2, bf##S##0, acc[2][0]); \
    acc[2][1] = MF(af##S##2, bf##S##1, acc[2][1]); \
    acc[3][0] = MF(af##S##3, bf##S##0, acc[3][0]); \
    acc[3][1] = MF(af##S##3, bf##S##1, acc[3][1]); \
    __builtin_amdgcn_s_setprio(0); }
#define BAR() __builtin_amdgcn_s_barrier()
#define SCHED0() __builtin_amdgcn_sched_barrier(0)
#define VMW4() asm volatile("s_waitcnt vmcnt(4)" ::: "memory")

    // prologue: stage planes pl0,pl1 (tile0) + pl2 (tile1); wait; prefetch P1
    SA(0, 0, 0); SB(0, 0, 0);
    SA(0, 1, 0); SB(0, 1, 0);
    SA(1, 0, 1); SB(1, 0, 1);
    asm volatile("s_waitcnt vmcnt(0)" ::: "memory");
    BAR();
    RD(A, 0, 0);

#pragma unroll 1
    for (int j = 0; j < K_DIM / 128; ++j) {
        const int t1 = 2 * j + 1;
        const int t2 = (2 * j + 2) & 63;
        const int t3 = (2 * j + 3) & 63;
        // P1
        MFMA8(A); VMW4();
        RD(B, 0, 1); SA(1, 1, t1);
        SCHED0(); BAR();
        // P2
        MFMA8(B);
        RD(A, 1, 0); SB(1, 1, t1);
        SCHED0(); BAR();
        // P3
        MFMA8(A); VMW4();
        RD(B, 1, 1); SA(0, 0, t2);
        SCHED0(); BAR();
        // P4
        MFMA8(B);
        RD(A, 2, 0); SB(0, 0, t2);
        SCHED0(); BAR();
        // P5
        MFMA8(A); VMW4();
        RD(B, 2, 1); SA(0, 1, t2);
        SCHED0(); BAR();
        // P6
        MFMA8(B);
        RD(A, 3, 0); SB(0, 1, t2);
        SCHED0(); BAR();
        // P7
        MFMA8(A); VMW4();
        RD(B, 3, 1); SA(1, 0, t3);
        SCHED0(); BAR();
        // P8
        MFMA8(B);
        RD(A, 0, 0); SB(1, 0, t3);
        SCHED0(); BAR();
    }

    // drain trailing prefetches so no gload lands in deallocated LDS
    asm volatile("s_waitcnt vmcnt(0)" ::: "memory");

    // epilogue: 32x32 C/D layout (r5-proven): col=lane&31,
    // row=(reg&3)+8*(reg>>2)+4*(lane>>5)
    const int colB = n0 + wn * 64 + (lane & 31);
    const int rowB = m0 + wm * 128 + ((lane >> 5) << 2);
#pragma unroll
    for (int n = 0; n < 2; ++n) {
        const int col = colB + n * 32;
        const float bv = bias[col];
#pragma unroll
        for (int m = 0; m < 4; ++m) {
            const f32x16 v = acc[m][n];
            float* o = out + (size_t)(rowB + m * 32) * N_OUT + col;
#pragma unroll
            for (int rg = 0; rg < 4; ++rg)
#pragma unroll
                for (int rr = 0; rr < 4; ++rr)
                    o[(size_t)(rg * 8 + rr) * N_OUT] = v[rg * 4 + rr] + bv;
        }
    }
#undef SA
#undef SB
#undef RD
#undef MF
#undef MFMA8
#undef BAR
#undef SCHED0
#undef VMW4
}

// ---------- correct-but-slow fallback (only if ws too small) ----------

__global__ __launch_bounds__(256) void fallback_kernel(const float* __restrict__ x,
                                                       const int* __restrict__ wq,
                                                       const float* __restrict__ qscale,
                                                       const float* __restrict__ qzero,
                                                       const float* __restrict__ theta,
                                                       const void* __restrict__ maskp,
                                                       const float* __restrict__ bias,
                                                       float* __restrict__ out) {
    __shared__ float xs[64][17];
    __shared__ float wsh[64][17];
    const int mi32 = mask_is_int32(maskp);
    const int n0 = blockIdx.x * 64, m0 = blockIdx.y * 64;
    const int t = threadIdx.x;
    const int tr = t >> 4, tc = t & 15;
    float acc[4][4] = {};

    for (int k0 = 0; k0 < K_DIM; k0 += 16) {
#pragma unroll
        for (int j = 0; j < 4; ++j) {
            int e = t * 4 + j;
            int r = e >> 4, c = e & 15;
            xs[r][c] = x[(size_t)(m0 + r) * K_DIM + k0 + c];
            int o = n0 + r;
            size_t idx = (size_t)o * K_DIM + k0 + c;
            float dq = ((float)wq[idx] - qzero[o]) * qscale[o];
            int mv = mi32 ? ((const int*)maskp)[idx] : ((const unsigned char*)maskp)[idx];
            wsh[r][c] = mv ? dq : theta[idx];
        }
        __syncthreads();
#pragma unroll
        for (int kk = 0; kk < 16; ++kk) {
            float a4[4], b4[4];
#pragma unroll
            for (int i = 0; i < 4; ++i) a4[i] = xs[tr * 4 + i][kk];
#pragma unroll
            for (int i = 0; i < 4; ++i) b4[i] = wsh[tc * 4 + i][kk];
#pragma unroll
            for (int i = 0; i < 4; ++i)
#pragma unroll
                for (int j = 0; j < 4; ++j) acc[i][j] += a4[i] * b4[j];
        }
        __syncthreads();
    }
#pragma unroll
    for (int i = 0; i < 4; ++i)
#pragma unroll
        for (int j = 0; j < 4; ++j)
            out[(size_t)(m0 + tr * 4 + i) * N_OUT + n0 + tc * 4 + j] =
                acc[i][j] + bias[n0 + tc * 4 + j];
}

// ---------- launch ----------

extern "C" void kernel_launch(void* const* d_in, const int* in_sizes, int n_in,
                              void* d_out, int out_size, void* d_ws, size_t ws_size,
                              hipStream_t stream) {
    const float* x      = (const float*)d_in[0];
    const int*   wq     = (const int*)d_in[1];
    const float* qscale = (const float*)d_in[2];
    const float* qzero  = (const float*)d_in[3];
    const float* theta  = (const float*)d_in[4];
    const void*  mask   = d_in[5];
    const float* bias   = (const float*)d_in[6];
    float* out = (float*)d_out;

    const size_t xb_bytes = (size_t)M_ROWS * K_DIM * 2;
    const size_t wb_bytes = (size_t)N_OUT * K_DIM * 2;

    if (ws_size >= xb_bytes + wb_bytes) {
        u16* xb = (u16*)d_ws;
        u16* wb = (u16*)((char*)d_ws + xb_bytes);
        prep_kernel<<<24576, 256, 0, stream>>>(x, xb, wq, qscale, qzero, theta, mask, wb);
        dim3 grid(N_OUT / 256, M_ROWS / 256);
        gemm8_kernel<<<grid, 512, 0, stream>>>(xb, wb, bias, out);
    } else {
        dim3 grid(N_OUT / 64, M_ROWS / 64);
        fallback_kernel<<<grid, 256, 0, stream>>>(x, wq, qscale, qzero, theta, mask, bias, out);
    }
}

// Round 13
// 318.745 us; speedup vs baseline: 1.2556x; 1.2556x over previous
//
#include <hip/hip_runtime.h>
#include <stdint.h>

typedef unsigned short u16;
typedef __bf16 bf16x8 __attribute__((ext_vector_type(8)));
typedef float f32x4 __attribute__((ext_vector_type(4)));

#define K_DIM 4096
#define N_OUT 4096
#define M_ROWS 8192

// ---------- helpers ----------

__device__ __forceinline__ u16 f2bf(float f) {
    uint32_t u = __builtin_bit_cast(uint32_t, f);
    u += 0x7fffu + ((u >> 16) & 1u);
    return (u16)(u >> 16);
}

__device__ __forceinline__ void gload_lds16(const void* g, void* l) {
    __builtin_amdgcn_global_load_lds(
        (const __attribute__((address_space(1))) void*)g,
        (__attribute__((address_space(3))) void*)l,
        16, 0, 0);
}

__device__ __forceinline__ int mask_is_int32(const void* maskp) {
    const uint32_t* u = (const uint32_t*)maskp;
    int ok = 1;
#pragma unroll
    for (int g = 0; g < 16; ++g) ok &= (u[g] <= 1u);
    return ok;
}

// ---------- fused prep kernel (r9; ~75us, at BW floor) ----------
// blocks [0, 16384): x f32 -> bf16 (8 elems/thread)
// blocks [16384, 24576): W_eff = mask ? (wq - qzero)*qscale : theta -> bf16

__global__ __launch_bounds__(256) void prep_kernel(const float* __restrict__ x,
                                                   u16* __restrict__ xb,
                                                   const int* __restrict__ wq,
                                                   const float* __restrict__ qscale,
                                                   const float* __restrict__ qzero,
                                                   const float* __restrict__ theta,
                                                   const void* __restrict__ maskp,
                                                   u16* __restrict__ wb) {
    if (blockIdx.x < 16384) {
        size_t t = (size_t)blockIdx.x * 256 + threadIdx.x;
        const float4* p = (const float4*)x + t * 2;
        float4 a = p[0], b = p[1];
        union { u16 u[8]; uint4 v; } o;
        o.u[0] = f2bf(a.x); o.u[1] = f2bf(a.y); o.u[2] = f2bf(a.z); o.u[3] = f2bf(a.w);
        o.u[4] = f2bf(b.x); o.u[5] = f2bf(b.y); o.u[6] = f2bf(b.z); o.u[7] = f2bf(b.w);
        ((uint4*)xb)[t] = o.v;
    } else {
        const int mi32 = mask_is_int32(maskp);
        size_t t = (size_t)(blockIdx.x - 16384) * 256 + threadIdx.x;
        size_t base = t * 8;
        int o = (int)(base >> 12);
        float s = qscale[o], z = qzero[o];

        int4 q0 = ((const int4*)wq)[t * 2];
        int4 q1 = ((const int4*)wq)[t * 2 + 1];
        float4 th0 = ((const float4*)theta)[t * 2];
        float4 th1 = ((const float4*)theta)[t * 2 + 1];

        int mv[8];
        if (mi32) {
            int4 m0 = ((const int4*)maskp)[t * 2];
            int4 m1 = ((const int4*)maskp)[t * 2 + 1];
            mv[0] = m0.x; mv[1] = m0.y; mv[2] = m0.z; mv[3] = m0.w;
            mv[4] = m1.x; mv[5] = m1.y; mv[6] = m1.z; mv[7] = m1.w;
        } else {
            uint2 mm = ((const uint2*)maskp)[t];
#pragma unroll
            for (int j = 0; j < 4; ++j) mv[j] = (mm.x >> (8 * j)) & 0xff;
#pragma unroll
            for (int j = 0; j < 4; ++j) mv[4 + j] = (mm.y >> (8 * j)) & 0xff;
        }

        float w[8];
        w[0] = mv[0] ? ((float)q0.x - z) * s : th0.x;
        w[1] = mv[1] ? ((float)q0.y - z) * s : th0.y;
        w[2] = mv[2] ? ((float)q0.z - z) * s : th0.z;
        w[3] = mv[3] ? ((float)q0.w - z) * s : th0.w;
        w[4] = mv[4] ? ((float)q1.x - z) * s : th1.x;
        w[5] = mv[5] ? ((float)q1.y - z) * s : th1.y;
        w[6] = mv[6] ? ((float)q1.z - z) * s : th1.z;
        w[7] = mv[7] ? ((float)q1.w - z) * s : th1.w;

        union { u16 u[8]; uint4 v; } ob;
#pragma unroll
        for (int j = 0; j < 8; ++j) ob.u[j] = f2bf(w[j]);
        ((uint4*)wb)[t] = ob.v;
    }
}

// ---------- 256x256 8-phase GEMM, 16x16x32, issue-first/wait-last (r13) ----------
//
// = r10 (best: 237us, MfmaUtil 57%) with ONE reorder on odd phases:
//   r10: {MFMA; VMW4; reads; SA}  ->  r13: {MFMA; reads; SA; VMW6}
// Equivalence proof (per-wave outstanding trace, steady state): at each odd
// phase, r10 has 8 outstanding at top, VMW4 completes the 4 oldest, SA -> 6;
// r13 has 8 at top, SA -> 10, VMW6 completes the 4 oldest — the SAME set.
// Every cross-wave read keeps its drain + >=1-barrier coverage (e.g. b1k1-B
// staged@P2, completed by P5's drain in both schemes, read@P6). Gain: reads
// and stage gloads issue BEFORE the wait — L2-burst drain delay overlaps
// their issue instead of delaying it.
// 32x32 shape abandoned for good (r12): its LDS region layout forces 16B/row
// scattered gload_lds sources (64 lines/instr vs 16) -> vmcnt stalls dominate.
// Frozen: LDS 128 KiB r3 swizzle (phys_slot = log_slot ^ ((row>>1)&3); write
// via pre-swizzled global chunk (l&3)^((l>>3)&3); 0 conflicts r3/r7/r9/r10),
// launch_bounds(512,2) (r8: (512,4) = spill catastrophe), read-ahead register
// pipeline (afA/afB, bfA/bfB), MFMA-first phases (r10).

__global__ __launch_bounds__(512, 2) void gemm8_kernel(const u16* __restrict__ xb,
                                                       const u16* __restrict__ wb,
                                                       const float* __restrict__ bias,
                                                       float* __restrict__ out) {
    __shared__ u16 lds[65536];  // 128 KiB: A planes [0,32768), B planes [32768,65536)

    const int tid = threadIdx.x;
    const int lane = tid & 63, wave = tid >> 6;
    const int wm = wave >> 2, wn = wave & 3;
    const int n0 = blockIdx.x * 256;
    const int m0 = blockIdx.y * 256;

    // fragment-read addressing (u16 units) — r3 proven pattern
    const int a_r = wm * 128 + (lane & 15);
    const int b_r = wn * 64 + (lane & 15);
    const int rslot = ((lane >> 4) ^ ((lane >> 1) & 3)) * 8;

    // stage addressing: wave w instr i covers chunk c=w*2+i = rows [c*16,+16)
    const int ch0 = wave * 2, ch1 = ch0 + 1;
    const int sRow = lane >> 2;
    const int sK = (((lane & 3) ^ ((lane >> 3) & 3)) * 8);
    const u16* gA0 = xb + (size_t)(m0 + ch0 * 16 + sRow) * K_DIM + sK;
    const u16* gA1 = xb + (size_t)(m0 + ch1 * 16 + sRow) * K_DIM + sK;
    const u16* gB0 = wb + (size_t)(n0 + ch0 * 16 + sRow) * K_DIM + sK;
    const u16* gB1 = wb + (size_t)(n0 + ch1 * 16 + sRow) * K_DIM + sK;

    f32x4 acc[8][4];
    const f32x4 zero = {0.f, 0.f, 0.f, 0.f};
#pragma unroll
    for (int m = 0; m < 8; ++m)
#pragma unroll
        for (int n = 0; n < 4; ++n) acc[m][n] = zero;

    // double-buffered fragment register sets (static names, rule #20)
    bf16x8 afA0, afA1, afA2, afA3, afB0, afB1, afB2, afB3;
    bf16x8 bfA0, bfA1, bfA2, bfA3, bfB0, bfB1, bfB2, bfB3;

#define SA(BUF, KH, KT) { \
    const size_t kofs = (size_t)((KT) * 64 + (KH) * 32); \
    const int pl = ((BUF) * 2 + (KH)) * 8192; \
    gload_lds16(gA0 + kofs, &lds[pl + ch0 * 512]); \
    gload_lds16(gA1 + kofs, &lds[pl + ch1 * 512]); }
#define SB(BUF, KH, KT) { \
    const size_t kofs = (size_t)((KT) * 64 + (KH) * 32); \
    const int pl = 32768 + ((BUF) * 2 + (KH)) * 8192; \
    gload_lds16(gB0 + kofs, &lds[pl + ch0 * 512]); \
    gload_lds16(gB1 + kofs, &lds[pl + ch1 * 512]); }
#define DAx(S, BUF, KS, MH) { \
    const int pa = ((BUF) * 2 + (KS)) * 8192 + (a_r + (MH) * 64) * 32 + rslot; \
    af##S##0 = *(const bf16x8*)&lds[pa]; \
    af##S##1 = *(const bf16x8*)&lds[pa + 512]; \
    af##S##2 = *(const bf16x8*)&lds[pa + 1024]; \
    af##S##3 = *(const bf16x8*)&lds[pa + 1536]; }
#define DBx(S, BUF, KS) { \
    const int pb = 32768 + ((BUF) * 2 + (KS)) * 8192 + b_r * 32 + rslot; \
    bf##S##0 = *(const bf16x8*)&lds[pb]; \
    bf##S##1 = *(const bf16x8*)&lds[pb + 512]; \
    bf##S##2 = *(const bf16x8*)&lds[pb + 1024]; \
    bf##S##3 = *(const bf16x8*)&lds[pb + 1536]; }
#define MF(A, B, C) __builtin_amdgcn_mfma_f32_16x16x32_bf16(A, B, C, 0, 0, 0)
#define MFMA16(MH, AS, BS) { \
    __builtin_amdgcn_s_setprio(1); \
    acc[(MH)*4+0][0] = MF(af##AS##0, bf##BS##0, acc[(MH)*4+0][0]); \
    acc[(MH)*4+0][1] = MF(af##AS##0, bf##BS##1, acc[(MH)*4+0][1]); \
    acc[(MH)*4+0][2] = MF(af##AS##0, bf##BS##2, acc[(MH)*4+0][2]); \
    acc[(MH)*4+0][3] = MF(af##AS##0, bf##BS##3, acc[(MH)*4+0][3]); \
    acc[(MH)*4+1][0] = MF(af##AS##1, bf##BS##0, acc[(MH)*4+1][0]); \
    acc[(MH)*4+1][1] = MF(af##AS##1, bf##BS##1, acc[(MH)*4+1][1]); \
    acc[(MH)*4+1][2] = MF(af##AS##1, bf##BS##2, acc[(MH)*4+1][2]); \
    acc[(MH)*4+1][3] = MF(af##AS##1, bf##BS##3, acc[(MH)*4+1][3]); \
    acc[(MH)*4+2][0] = MF(af##AS##2, bf##BS##0, acc[(MH)*4+2][0]); \
    acc[(MH)*4+2][1] = MF(af##AS##2, bf##BS##1, acc[(MH)*4+2][1]); \
    acc[(MH)*4+2][2] = MF(af##AS##2, bf##BS##2, acc[(MH)*4+2][2]); \
    acc[(MH)*4+2][3] = MF(af##AS##2, bf##BS##3, acc[(MH)*4+2][3]); \
    acc[(MH)*4+3][0] = MF(af##AS##3, bf##BS##0, acc[(MH)*4+3][0]); \
    acc[(MH)*4+3][1] = MF(af##AS##3, bf##BS##1, acc[(MH)*4+3][1]); \
    acc[(MH)*4+3][2] = MF(af##AS##3, bf##BS##2, acc[(MH)*4+3][2]); \
    acc[(MH)*4+3][3] = MF(af##AS##3, bf##BS##3, acc[(MH)*4+3][3]); \
    __builtin_amdgcn_s_setprio(0); }
#define BAR() __builtin_amdgcn_s_barrier()
#define SCHED0() __builtin_amdgcn_sched_barrier(0)
#define VMW6() asm volatile("s_waitcnt vmcnt(6)" ::: "memory")

    // prologue: tile0 full + tile1 khalf0, then prefetch P1's fragments
    SA(0, 0, 0); SB(0, 0, 0);
    SA(0, 1, 0); SB(0, 1, 0);
    SA(1, 0, 1); SB(1, 0, 1);
    asm volatile("s_waitcnt vmcnt(0)" ::: "memory");
    BAR();
    DBx(A, 0, 0); DAx(A, 0, 0, 0);

#pragma unroll 1
    for (int j = 0; j < K_DIM / 128; ++j) {
        const int t1 = 2 * j + 1;
        const int t2 = (2 * j + 2) & 63;
        const int t3 = (2 * j + 3) & 63;
        // P1: MFMA (afA,bfA); prefetch afB<-b0k0 MH1; stage; wait-last
        MFMA16(0, A, A);
        DAx(B, 0, 0, 1); SA(1, 1, t1);
        VMW6();
        SCHED0(); BAR();
        // P2: MFMA (afB,bfA); prefetch afA,bfB <- b0k1 MH0
        MFMA16(1, B, A);
        DAx(A, 0, 1, 0); DBx(B, 0, 1); SB(1, 1, t1);
        SCHED0(); BAR();
        // P3
        MFMA16(0, A, B);
        DAx(B, 0, 1, 1); SA(0, 0, t2);
        VMW6();
        SCHED0(); BAR();
        // P4
        MFMA16(1, B, B);
        DAx(A, 1, 0, 0); DBx(A, 1, 0); SB(0, 0, t2);
        SCHED0(); BAR();
        // P5
        MFMA16(0, A, A);
        DAx(B, 1, 0, 1); SA(0, 1, t2);
        VMW6();
        SCHED0(); BAR();
        // P6
        MFMA16(1, B, A);
        DAx(A, 1, 1, 0); DBx(B, 1, 1); SB(0, 1, t2);
        SCHED0(); BAR();
        // P7
        MFMA16(0, A, B);
        DAx(B, 1, 1, 1); SA(1, 0, t3);
        VMW6();
        SCHED0(); BAR();
        // P8
        MFMA16(1, B, B);
        DAx(A, 0, 0, 0); DBx(A, 0, 0); SB(1, 0, t3);
        SCHED0(); BAR();
    }

    // drain trailing prefetches so no gload lands in deallocated LDS
    asm volatile("s_waitcnt vmcnt(0)" ::: "memory");

    // epilogue: C/D layout col=lane&15, row=(lane>>4)*4+reg
    const int rowBase = m0 + wm * 128 + ((lane >> 4) << 2);
    const int colBase = n0 + wn * 64 + (lane & 15);
#pragma unroll
    for (int n = 0; n < 4; ++n) {
        const int col = colBase + n * 16;
        const float bv = bias[col];
#pragma unroll
        for (int m = 0; m < 8; ++m) {
            const f32x4 v = acc[m][n];
            float* o = out + (size_t)(rowBase + m * 16) * N_OUT + col;
            o[0] = v[0] + bv;
            o[N_OUT] = v[1] + bv;
            o[2 * N_OUT] = v[2] + bv;
            o[3 * N_OUT] = v[3] + bv;
        }
    }
#undef SA
#undef SB
#undef DAx
#undef DBx
#undef MF
#undef MFMA16
#undef BAR
#undef SCHED0
#undef VMW6
}

// ---------- correct-but-slow fallback (only if ws too small) ----------

__global__ __launch_bounds__(256) void fallback_kernel(const float* __restrict__ x,
                                                       const int* __restrict__ wq,
                                                       const float* __restrict__ qscale,
                                                       const float* __restrict__ qzero,
                                                       const float* __restrict__ theta,
                                                       const void* __restrict__ maskp,
                                                       const float* __restrict__ bias,
                                                       float* __restrict__ out) {
    __shared__ float xs[64][17];
    __shared__ float wsh[64][17];
    const int mi32 = mask_is_int32(maskp);
    const int n0 = blockIdx.x * 64, m0 = blockIdx.y * 64;
    const int t = threadIdx.x;
    const int tr = t >> 4, tc = t & 15;
    float acc[4][4] = {};

    for (int k0 = 0; k0 < K_DIM; k0 += 16) {
#pragma unroll
        for (int j = 0; j < 4; ++j) {
            int e = t * 4 + j;
            int r = e >> 4, c = e & 15;
            xs[r][c] = x[(size_t)(m0 + r) * K_DIM + k0 + c];
            int o = n0 + r;
            size_t idx = (size_t)o * K_DIM + k0 + c;
            float dq = ((float)wq[idx] - qzero[o]) * qscale[o];
            int mv = mi32 ? ((const int*)maskp)[idx] : ((const unsigned char*)maskp)[idx];
            wsh[r][c] = mv ? dq : theta[idx];
        }
        __syncthreads();
#pragma unroll
        for (int kk = 0; kk < 16; ++kk) {
            float a4[4], b4[4];
#pragma unroll
            for (int i = 0; i < 4; ++i) a4[i] = xs[tr * 4 + i][kk];
#pragma unroll
            for (int i = 0; i < 4; ++i) b4[i] = wsh[tc * 4 + i][kk];
#pragma unroll
            for (int i = 0; i < 4; ++i)
#pragma unroll
                for (int j = 0; j < 4; ++j) acc[i][j] += a4[i] * b4[j];
        }
        __syncthreads();
    }
#pragma unroll
    for (int i = 0; i < 4; ++i)
#pragma unroll
        for (int j = 0; j < 4; ++j)
            out[(size_t)(m0 + tr * 4 + i) * N_OUT + n0 + tc * 4 + j] =
                acc[i][j] + bias[n0 + tc * 4 + j];
}

// ---------- launch ----------

extern "C" void kernel_launch(void* const* d_in, const int* in_sizes, int n_in,
                              void* d_out, int out_size, void* d_ws, size_t ws_size,
                              hipStream_t stream) {
    const float* x      = (const float*)d_in[0];
    const int*   wq     = (const int*)d_in[1];
    const float* qscale = (const float*)d_in[2];
    const float* qzero  = (const float*)d_in[3];
    const float* theta  = (const float*)d_in[4];
    const void*  mask   = d_in[5];
    const float* bias   = (const float*)d_in[6];
    float* out = (float*)d_out;

    const size_t xb_bytes = (size_t)M_ROWS * K_DIM * 2;
    const size_t wb_bytes = (size_t)N_OUT * K_DIM * 2;

    if (ws_size >= xb_bytes + wb_bytes) {
        u16* xb = (u16*)d_ws;
        u16* wb = (u16*)((char*)d_ws + xb_bytes);
        prep_kernel<<<24576, 256, 0, stream>>>(x, xb, wq, qscale, qzero, theta, mask, wb);
        dim3 grid(N_OUT / 256, M_ROWS / 256);
        gemm8_kernel<<<grid, 512, 0, stream>>>(xb, wb, bias, out);
    } else {
        dim3 grid(N_OUT / 64, M_ROWS / 64);
        fallback_kernel<<<grid, 256, 0, stream>>>(x, wq, qscale, qzero, theta, mask, bias, out);
    }
}